// Round 1
// baseline (276.246 us; speedup 1.0000x reference)
//
#include <hip/hip_runtime.h>

// PointTransformerLayer fused kernel (MI355X / gfx950)
//
// Refactoring:
//   relu1 = relu(aI_i - a_j)            aI = pos@pW1 + pb1, a = pos@pW1
//   S1    = [relu1 | (q_i - k_j)] @ [[W_pa],[aW1]]   (K=128), W_pa = pW2@aW1
//   H     = relu(S1 + c), c = ab1 + pb2@aW1
//   sim   = H @ aW2                      (ab2 dropped: softmax-invariant over j)
//   rpe   = relu1 @ pW2 ; vv = (v+pb2)_j + rpe
//   out_i[d] = sum_j exp(sim) * vv / sum_j exp(sim)   (per-channel softmax, no
//              max-subtraction: sim ~ N(0,1), fp32 exp/sums are exact enough)
//
// One block per i (4 waves, 256 thr), j-loop in tiles of 16 (M-dim = j).
// MFMA 16x16x32 bf16; H goes C-layout -> LDS -> A-layout (m120 pattern) with a
// column permutation so writes are b64 and reads are b128 (aW2 frags row-
// permuted to match at prep time). Row stride 528 B = bank-conflict floor.

using sh8   = __attribute__((ext_vector_type(8))) short;  // 8 bf16 (4 VGPRs)
using f32x4 = __attribute__((ext_vector_type(4))) float;

static constexpr int NPTS = 1024;

// ---- ws layout (bytes) ----
static constexpr size_t BEXT_OFF = 0;        // 4*16*64*8 bf16  = 65536 B
static constexpr size_t AW2F_OFF = 65536;    // 8*4*64*8 bf16   = 32768 B
static constexpr size_t PW2F_OFF = 98304;    // 2*4*64*8 bf16   = 8192 B
static constexpr size_t CARR_OFF = 106496;   // 256 f32         = 1024 B
static constexpr size_t AI_OFF   = 107520;   // 1024*64 f32 (+pb1)
static constexpr size_t QI_OFF   = 369664;   // 1024*64 f32
static constexpr size_t VP_OFF   = 631808;   // 1024*64 f32 (+pb2)
static constexpr size_t AJ_OFF   = 893952;   // 1024*64 bf16
static constexpr size_t KN_OFF   = 1025024;  // 1024*64 bf16 (negated k)

__device__ __forceinline__ unsigned short f2b_rne(float f) {
    unsigned u = __float_as_uint(f);
    u += 0x7fffu + ((u >> 16) & 1u);
    return (unsigned short)(u >> 16);
}
__device__ __forceinline__ unsigned pk2(float lo, float hi) {  // trunc-pack 2xbf16
    return (__float_as_uint(lo) >> 16) | (__float_as_uint(hi) & 0xffff0000u);
}
__device__ __forceinline__ float b2f(unsigned short s) {
    return __uint_as_float(((unsigned)s) << 16);
}

// ---------------- weight prep: fused/fragment-packed constants ----------------
__global__ void prep_weights(const float* __restrict__ pW2, const float* __restrict__ aW1,
                             const float* __restrict__ aW2, const float* __restrict__ ab1,
                             const float* __restrict__ pb2,
                             unsigned short* __restrict__ bextf, unsigned short* __restrict__ aw2f,
                             unsigned short* __restrict__ pw2f, float* __restrict__ cArr)
{
    const int gtid = blockIdx.x * blockDim.x + threadIdx.x;
    const int gstr = gridDim.x * blockDim.x;

    // B_ext fragments: tile = kc*16 + ntg; rows k<64 -> W_pa=pW2@aW1, k>=64 -> aW1
    for (int idx = gtid; idx < 4 * 16 * 64; idx += gstr) {
        const int lane = idx & 63;
        const int tile = idx >> 6;
        const int kc = tile >> 4, ntg = tile & 15;
        const int kbase = kc * 32 + (lane >> 4) * 8;
        const int t = ntg * 16 + (lane & 15);
        unsigned short* dst = bextf + (size_t)idx * 8;
#pragma unroll
        for (int e = 0; e < 8; ++e) {
            const int k = kbase + e;
            float val;
            if (k < 64) {
                float s = 0.f;
                for (int d = 0; d < 64; ++d) s = fmaf(pW2[k * 64 + d], aW1[d * 256 + t], s);
                val = s;
            } else {
                val = aW1[(k - 64) * 256 + t];
            }
            dst[e] = f2b_rne(val);
        }
    }
    // aW2 fragments with permuted K (matches H_perm LDS layout): tile = kc*4 + nt
    for (int idx = gtid; idx < 8 * 4 * 64; idx += gstr) {
        const int lane = idx & 63;
        const int tile = idx >> 6;
        const int kc = tile >> 2, nt = tile & 3;
        const int d = nt * 16 + (lane & 15);
        unsigned short* dst = aw2f + (size_t)idx * 8;
#pragma unroll
        for (int e = 0; e < 8; ++e) {
            const int kp = kc * 32 + (lane >> 4) * 8 + e;
            const int t = 64 * (kp >> 6) + 16 * (kp & 3) + ((kp >> 2) & 15); // inv perm
            dst[e] = f2b_rne(aW2[t * 64 + d]);
        }
    }
    // pW2 fragments (normal K order): tile = kc*4 + nt
    for (int idx = gtid; idx < 2 * 4 * 64; idx += gstr) {
        const int lane = idx & 63;
        const int tile = idx >> 6;
        const int kc = tile >> 2, nt = tile & 3;
        const int d = nt * 16 + (lane & 15);
        unsigned short* dst = pw2f + (size_t)idx * 8;
#pragma unroll
        for (int e = 0; e < 8; ++e) {
            const int k = kc * 32 + (lane >> 4) * 8 + e;
            dst[e] = f2b_rne(pW2[k * 64 + d]);
        }
    }
    // c = ab1 + pb2@aW1
    if (gtid < 256) {
        const int t = gtid;
        float s = ab1[t];
        for (int d = 0; d < 64; ++d) s = fmaf(pb2[d], aW1[d * 256 + t], s);
        cArr[t] = s;
    }
}

// ---------------- per-point prep: q, -k, v+pb2, a(+pb1) ----------------
__global__ void prep_points(const float* __restrict__ x, const float* __restrict__ pos,
                            const float* __restrict__ Wq, const float* __restrict__ Wk,
                            const float* __restrict__ Wv, const float* __restrict__ pW1,
                            const float* __restrict__ pb1, const float* __restrict__ pb2,
                            float* __restrict__ qI, unsigned short* __restrict__ kN,
                            float* __restrict__ vP, float* __restrict__ aI,
                            unsigned short* __restrict__ aJ)
{
    const int i = blockIdx.x, d = threadIdx.x;
    __shared__ float xs[64];
    xs[d] = x[i * 64 + d];
    __syncthreads();
    float q = 0.f, k = 0.f, v = 0.f;
    for (int e = 0; e < 64; ++e) {
        const float xe = xs[e];
        q = fmaf(xe, Wq[e * 64 + d], q);
        k = fmaf(xe, Wk[e * 64 + d], k);
        v = fmaf(xe, Wv[e * 64 + d], v);
    }
    const float a = pos[i * 2] * pW1[d] + pos[i * 2 + 1] * pW1[64 + d];
    qI[i * 64 + d] = q;
    kN[i * 64 + d] = f2b_rne(-k);
    vP[i * 64 + d] = v + pb2[d];
    aI[i * 64 + d] = a + pb1[d];
    aJ[i * 64 + d] = f2b_rne(a);
}

// ---------------- main fused kernel: one block per query i ----------------
__global__ __launch_bounds__(256, 2) void ptl_main(
    const float* __restrict__ aI, const float* __restrict__ qI,
    const unsigned short* __restrict__ aJ, const unsigned short* __restrict__ kN,
    const float* __restrict__ vP,
    const unsigned short* __restrict__ bextf, const unsigned short* __restrict__ aw2f,
    const unsigned short* __restrict__ pw2f, const float* __restrict__ cArr,
    float* __restrict__ out)
{
    const int i    = blockIdx.x;
    const int tid  = threadIdx.x;
    const int w    = tid >> 6;    // wave 0..3: owns t-cols [64w,64w+64), d-cols [16w,16w+16)
    const int lane = tid & 63;
    const int m    = lane & 15;
    const int q    = lane >> 4;

    __shared__ __align__(16) unsigned char Hs[16 * 528];  // H_perm: 16 rows x 264 bf16

    // constant B fragments (registers, loaded once per block)
    sh8 Bf[16];
#pragma unroll
    for (int kc = 0; kc < 4; ++kc)
#pragma unroll
        for (int nt = 0; nt < 4; ++nt)
            Bf[kc * 4 + nt] = *(const sh8*)(bextf + ((size_t)((kc * 16 + 4 * w + nt) * 64 + lane)) * 8);
    sh8 W2f[8];
#pragma unroll
    for (int kc = 0; kc < 8; ++kc)
        W2f[kc] = *(const sh8*)(aw2f + ((size_t)((kc * 4 + w) * 64 + lane)) * 8);
    sh8 P2f[2];
#pragma unroll
    for (int kc = 0; kc < 2; ++kc)
        P2f[kc] = *(const sh8*)(pw2f + ((size_t)((kc * 4 + w) * 64 + lane)) * 8);

    // per-block i-side values
    float aif[16], qif[16];
#pragma unroll
    for (int kc = 0; kc < 2; ++kc)
#pragma unroll
        for (int e = 0; e < 8; ++e) {
            aif[kc * 8 + e] = aI[i * 64 + kc * 32 + q * 8 + e];
            qif[kc * 8 + e] = qI[i * 64 + kc * 32 + q * 8 + e];
        }
    float creg[4];
#pragma unroll
    for (int nt = 0; nt < 4; ++nt) creg[nt] = cArr[64 * w + 16 * nt + m];

    float num = 0.f, den = 0.f;
    const f32x4 z4 = {0.f, 0.f, 0.f, 0.f};

    const unsigned short* aJp = aJ + m * 64 + q * 8;
    const unsigned short* kNp = kN + m * 64 + q * 8;
    const float*          vPp = vP + (4 * q) * 64 + 16 * w + m;

    for (int j0 = 0; j0 < NPTS; j0 += 16) {
        // A fragments: kc0,1 = relu1 ; kc2,3 = q_i - k_j
        sh8 Af[4];
#pragma unroll
        for (int kc = 0; kc < 2; ++kc) {
            const sh8 av = *(const sh8*)(aJp + j0 * 64 + kc * 32);
            const sh8 kv = *(const sh8*)(kNp + j0 * 64 + kc * 32);
            float r[8], s[8];
#pragma unroll
            for (int e = 0; e < 8; ++e) {
                r[e] = fmaxf(aif[kc * 8 + e] - b2f((unsigned short)av[e]), 0.f);
                s[e] = qif[kc * 8 + e] + b2f((unsigned short)kv[e]);
            }
            union { sh8 v; unsigned u[4]; } pr, ps;
#pragma unroll
            for (int t = 0; t < 4; ++t) {
                pr.u[t] = pk2(r[2 * t], r[2 * t + 1]);
                ps.u[t] = pk2(s[2 * t], s[2 * t + 1]);
            }
            Af[kc]     = pr.v;
            Af[2 + kc] = ps.v;
        }

        // G1: S1[j, t-slice] (K=128)
        f32x4 acc[4] = {z4, z4, z4, z4};
#pragma unroll
        for (int kc = 0; kc < 4; ++kc) {
#pragma unroll
            for (int nt = 0; nt < 4; ++nt)
                acc[nt] = __builtin_amdgcn_mfma_f32_16x16x32_bf16(Af[kc], Bf[kc * 4 + nt], acc[nt], 0, 0, 0);
        }

        // H = relu(S1 + c) -> LDS (permuted columns t' = 64w + 4m + nt, b64 writes)
        __syncthreads();  // prior step's reads complete
        {
            unsigned char* hw = Hs + (4 * q) * 528 + 128 * w + 8 * m;
#pragma unroll
            for (int r = 0; r < 4; ++r) {
                const float h0 = fmaxf(acc[0][r] + creg[0], 0.f);
                const float h1 = fmaxf(acc[1][r] + creg[1], 0.f);
                const float h2 = fmaxf(acc[2][r] + creg[2], 0.f);
                const float h3 = fmaxf(acc[3][r] + creg[3], 0.f);
                uint2 pk;
                pk.x = pk2(h0, h1);
                pk.y = pk2(h2, h3);
                *(uint2*)(hw + r * 528) = pk;
            }
        }
        __syncthreads();  // H visible to all waves

        // G2: sim[j, d-slice] (K=256, permuted k matches aw2f)
        f32x4 accS = z4;
#pragma unroll
        for (int kc = 0; kc < 8; ++kc) {
            const sh8 hf = *(const sh8*)(Hs + m * 528 + kc * 64 + 16 * q);
            accS = __builtin_amdgcn_mfma_f32_16x16x32_bf16(hf, W2f[kc], accS, 0, 0, 0);
        }
        // G3: rpe[j, d-slice] (K=64)
        f32x4 accR = z4;
        accR = __builtin_amdgcn_mfma_f32_16x16x32_bf16(Af[0], P2f[0], accR, 0, 0, 0);
        accR = __builtin_amdgcn_mfma_f32_16x16x32_bf16(Af[1], P2f[1], accR, 0, 0, 0);

        // online accumulation: num += exp(sim)*vv ; den += exp(sim)
        const float* vr = vPp + j0 * 64;
#pragma unroll
        for (int r = 0; r < 4; ++r) {
            const float ex = __expf(accS[r]);
            const float vv = accR[r] + vr[r * 64];
            num = fmaf(ex, vv, num);
            den += ex;
        }
    }

    // reduce the 4 quad-partials (lanes m, m+16, m+32, m+48)
    num += __shfl_xor(num, 16);
    num += __shfl_xor(num, 32);
    den += __shfl_xor(den, 16);
    den += __shfl_xor(den, 32);
    if (q == 0) out[i * 64 + 16 * w + m] = num / den;
}

extern "C" void kernel_launch(void* const* d_in, const int* in_sizes, int n_in,
                              void* d_out, int out_size, void* d_ws, size_t ws_size,
                              hipStream_t stream) {
    const float* x   = (const float*)d_in[0];
    const float* pos = (const float*)d_in[1];
    const float* Wq  = (const float*)d_in[2];
    const float* Wk  = (const float*)d_in[3];
    const float* Wv  = (const float*)d_in[4];
    const float* pW1 = (const float*)d_in[5];
    const float* pb1 = (const float*)d_in[6];
    const float* pW2 = (const float*)d_in[7];
    const float* pb2 = (const float*)d_in[8];
    const float* aW1 = (const float*)d_in[9];
    const float* ab1 = (const float*)d_in[10];
    const float* aW2 = (const float*)d_in[11];
    // d_in[12] = ab2: constant over j -> cancels in per-channel softmax, unused.

    char* ws = (char*)d_ws;
    unsigned short* bextf = (unsigned short*)(ws + BEXT_OFF);
    unsigned short* aw2f  = (unsigned short*)(ws + AW2F_OFF);
    unsigned short* pw2f  = (unsigned short*)(ws + PW2F_OFF);
    float*          cArr  = (float*)(ws + CARR_OFF);
    float*          aIa   = (float*)(ws + AI_OFF);
    float*          qIa   = (float*)(ws + QI_OFF);
    float*          vPa   = (float*)(ws + VP_OFF);
    unsigned short* aJa   = (unsigned short*)(ws + AJ_OFF);
    unsigned short* kNa   = (unsigned short*)(ws + KN_OFF);

    prep_weights<<<16, 256, 0, stream>>>(pW2, aW1, aW2, ab1, pb2, bextf, aw2f, pw2f, cArr);
    prep_points<<<NPTS, 64, 0, stream>>>(x, pos, Wq, Wk, Wv, pW1, pb1, pb2, qIa, kNa, vPa, aIa, aJa);
    ptl_main<<<NPTS, 256, 0, stream>>>(aIa, qIa, aJa, kNa, vPa, bextf, aw2f, pw2f, cArr, (float*)d_out);
}

// Round 2
// 216.986 us; speedup vs baseline: 1.2731x; 1.2731x over previous
//
#include <hip/hip_runtime.h>

// PointTransformerLayer fused kernel (MI355X / gfx950) — round 2
//
// Math (verified round 1, absmax 0.031):
//   relu1 = relu(aI_i - a_j)            aI = pos@pW1 + pb1, a = pos@pW1
//   S1    = [relu1 | (q_i - k_j)] @ [[W_pa],[aW1]]   (K=128), W_pa = pW2@aW1
//   H     = relu(S1 + c), c = ab1 + pb2@aW1
//   sim   = H @ aW2                      (ab2 dropped: softmax-invariant over j)
//   rpe   = relu1 @ pW2 ; vv = (v+pb2)_j + rpe
//   out_i[d] = sum_j exp(sim)*vv / sum_j exp(sim)
//
// Round-2 structure changes (same math, same fragment layouts):
//   - ONE __syncthreads per j-iter: H and Af double-buffered in LDS.
//   - wave-specialized Af build: wave w builds fragment w (w<2: relu1 halves,
//     w>=2: q-k halves) for iter n+1, publishes via LDS; 4x less VALU + 4x
//     less aJ/kN L2 traffic than every-wave-builds-everything.
//   - vPT = (v+pb2)^T [d][j] so the softmax epilogue is one dwordx4.
//   - prep_weights made element-parallel (was 512-deep fmaf chains).

using sh8   = __attribute__((ext_vector_type(8))) short;  // 8 bf16 (4 VGPRs)
using f32x4 = __attribute__((ext_vector_type(4))) float;

static constexpr int NPTS = 1024;

// ---- ws layout (bytes) ----
static constexpr size_t BEXT_OFF = 0;        // 4*16*64*8 bf16  = 65536 B
static constexpr size_t AW2F_OFF = 65536;    // 8*4*64*8 bf16   = 32768 B
static constexpr size_t PW2F_OFF = 98304;    // 2*4*64*8 bf16   = 8192 B
static constexpr size_t CARR_OFF = 106496;   // 256 f32         = 1024 B
static constexpr size_t AI_OFF   = 107520;   // 1024*64 f32 (+pb1)
static constexpr size_t QI_OFF   = 369664;   // 1024*64 f32
static constexpr size_t VPT_OFF  = 631808;   // 64*1024 f32 (v+pb2, transposed)
static constexpr size_t AJ_OFF   = 893952;   // 1024*64 bf16
static constexpr size_t KN_OFF   = 1025024;  // 1024*64 bf16 (negated k)

__device__ __forceinline__ unsigned short f2b_rne(float f) {
    unsigned u = __float_as_uint(f);
    u += 0x7fffu + ((u >> 16) & 1u);
    return (unsigned short)(u >> 16);
}
__device__ __forceinline__ unsigned pk2(float lo, float hi) {  // trunc-pack 2xbf16
    return (__float_as_uint(lo) >> 16) | (__float_as_uint(hi) & 0xffff0000u);
}
__device__ __forceinline__ float b2f(unsigned short s) {
    return __uint_as_float(((unsigned)s) << 16);
}

// ---------------- weight prep: element-parallel fragment packing ----------------
// work items: [0,32768)            B_ext (k,t), k<128, t<256
//             [32768,49152)        aw2f  (kp,d), kp<256 permuted, d<64
//             [49152,53248)        pw2f  (k,d), k<64, d<64
//             [53248,53504)        cArr  (t)
__global__ void prep_weights(const float* __restrict__ pW2, const float* __restrict__ aW1,
                             const float* __restrict__ aW2, const float* __restrict__ ab1,
                             const float* __restrict__ pb2,
                             unsigned short* __restrict__ bextf, unsigned short* __restrict__ aw2f,
                             unsigned short* __restrict__ pw2f, float* __restrict__ cArr)
{
    const int idx = blockIdx.x * blockDim.x + threadIdx.x;
    if (idx < 32768) {
        const int k = idx >> 8, t = idx & 255;
        float val;
        if (k < 64) {
            float s = 0.f;
            for (int d = 0; d < 64; ++d) s = fmaf(pW2[k * 64 + d], aW1[d * 256 + t], s);
            val = s;
        } else {
            val = aW1[(k - 64) * 256 + t];
        }
        const int kc = k >> 5, kl = k & 31, qq = kl >> 3, e = kl & 7;
        const int ntg = t >> 4, tl = t & 15;
        bextf[(((size_t)(kc * 16 + ntg) * 64) + (qq * 16 + tl)) * 8 + e] = f2b_rne(val);
    } else if (idx < 49152) {
        const int r = idx - 32768;
        const int kp = r >> 6, d = r & 63;
        const int t = 64 * (kp >> 6) + 16 * (kp & 3) + ((kp >> 2) & 15);  // inverse perm
        const int kc = kp >> 5, kl = kp & 31, qq = kl >> 3, e = kl & 7;
        const int nt = d >> 4, dl = d & 15;
        aw2f[(((size_t)(kc * 4 + nt) * 64) + (qq * 16 + dl)) * 8 + e] = f2b_rne(aW2[t * 64 + d]);
    } else if (idx < 53248) {
        const int r = idx - 49152;
        const int k = r >> 6, d = r & 63;
        const int kc = k >> 5, kl = k & 31, qq = kl >> 3, e = kl & 7;
        const int nt = d >> 4, dl = d & 15;
        pw2f[(((size_t)(kc * 4 + nt) * 64) + (qq * 16 + dl)) * 8 + e] = f2b_rne(pW2[k * 64 + d]);
    } else if (idx < 53504) {
        const int t = idx - 53248;
        float s = ab1[t];
        for (int d = 0; d < 64; ++d) s = fmaf(pb2[d], aW1[d * 256 + t], s);
        cArr[t] = s;
    }
}

// ---------------- per-point prep: q, -k, (v+pb2)^T, a(+pb1) ----------------
__global__ void prep_points(const float* __restrict__ x, const float* __restrict__ pos,
                            const float* __restrict__ Wq, const float* __restrict__ Wk,
                            const float* __restrict__ Wv, const float* __restrict__ pW1,
                            const float* __restrict__ pb1, const float* __restrict__ pb2,
                            float* __restrict__ qI, unsigned short* __restrict__ kN,
                            float* __restrict__ vPT, float* __restrict__ aI,
                            unsigned short* __restrict__ aJ)
{
    const int i = blockIdx.x, d = threadIdx.x;
    __shared__ float xs[64];
    xs[d] = x[i * 64 + d];
    __syncthreads();
    float q = 0.f, k = 0.f, v = 0.f;
    for (int e = 0; e < 64; ++e) {
        const float xe = xs[e];
        q = fmaf(xe, Wq[e * 64 + d], q);
        k = fmaf(xe, Wk[e * 64 + d], k);
        v = fmaf(xe, Wv[e * 64 + d], v);
    }
    const float a = pos[i * 2] * pW1[d] + pos[i * 2 + 1] * pW1[64 + d];
    qI[i * 64 + d] = q;
    kN[i * 64 + d] = f2b_rne(-k);
    vPT[d * NPTS + i] = v + pb2[d];
    aI[i * 64 + d] = a + pb1[d];
    aJ[i * 64 + d] = f2b_rne(a);
}

// ---------------- main fused kernel: one block per query i ----------------
__global__ __launch_bounds__(256, 2) void ptl_main(
    const float* __restrict__ aI, const float* __restrict__ qI,
    const unsigned short* __restrict__ aJ, const unsigned short* __restrict__ kN,
    const float* __restrict__ vPT,
    const unsigned short* __restrict__ bextf, const unsigned short* __restrict__ aw2f,
    const unsigned short* __restrict__ pw2f, const float* __restrict__ cArr,
    float* __restrict__ out)
{
    const int i    = blockIdx.x;
    const int tid  = threadIdx.x;
    const int w    = tid >> 6;    // wave 0..3
    const int lane = tid & 63;
    const int m    = lane & 15;
    const int q    = lane >> 4;

    // double-buffered LDS: Af fragments (built by specialized waves) + H
    __shared__ __align__(16) uint4 AfL[2][4][64];                 // 8 KB
    __shared__ __align__(16) unsigned char Hs[2][16 * 528];       // 16.5 KB

    // constant B fragments (registers/AGPRs, loaded once per block)
    sh8 Bf[16];
#pragma unroll
    for (int kc = 0; kc < 4; ++kc)
#pragma unroll
        for (int nt = 0; nt < 4; ++nt)
            Bf[kc * 4 + nt] = *(const sh8*)(bextf + ((size_t)((kc * 16 + 4 * w + nt) * 64 + lane)) * 8);
    sh8 W2f[8];
#pragma unroll
    for (int kc = 0; kc < 8; ++kc)
        W2f[kc] = *(const sh8*)(aw2f + ((size_t)((kc * 4 + w) * 64 + lane)) * 8);
    sh8 P2f[2];
#pragma unroll
    for (int kc = 0; kc < 2; ++kc)
        P2f[kc] = *(const sh8*)(pw2f + ((size_t)((kc * 4 + w) * 64 + lane)) * 8);

    float creg[4];
#pragma unroll
    for (int nt = 0; nt < 4; ++nt) creg[nt] = cArr[64 * w + 16 * nt + m];

    // builder setup: wave w builds fragment w.
    //   w=0: relu1 k[0:32)   w=1: relu1 k[32:64)   w=2: q-k k[0:32)   w=3: q-k k[32:64)
    const int  half   = w & 1;
    const bool isRelu = (w < 2);
    const unsigned short* bsrc  = (isRelu ? aJ : kN) + m * 64 + half * 32 + q * 8;
    const float*          ibase = (isRelu ? aI : qI) + i * 64 + half * 32 + q * 8;
    float iv[8];
    *(float4*)(iv)     = *(const float4*)(ibase);
    *(float4*)(iv + 4) = *(const float4*)(ibase + 4);

    // prologue: build Af(0) into buffer 0
    {
        const sh8 raw = *(const sh8*)(bsrc);
        float t[8];
#pragma unroll
        for (int e = 0; e < 8; ++e)
            t[e] = isRelu ? fmaxf(iv[e] - b2f((unsigned short)raw[e]), 0.f)
                          : iv[e] + b2f((unsigned short)raw[e]);
        uint4 pk;
        pk.x = pk2(t[0], t[1]); pk.y = pk2(t[2], t[3]);
        pk.z = pk2(t[4], t[5]); pk.w = pk2(t[6], t[7]);
        AfL[0][w][lane] = pk;
    }
    __syncthreads();

    float num = 0.f, den = 0.f;
    const f32x4 z4 = {0.f, 0.f, 0.f, 0.f};
    const float* vbase = vPT + (size_t)(16 * w + m) * NPTS;

    for (int n = 0; n < 64; ++n) {
        const int pb = n & 1, nb = pb ^ 1;
        const int j0 = n << 4;

        // issue next tile's raw load early (hidden under G1)
        sh8 raw;
        if (n < 63) raw = *(const sh8*)(bsrc + (size_t)(j0 + 16) * 64);

        // current Af fragments from LDS (conflict-free: lane-contiguous 16B)
        const sh8 Af0 = *(const sh8*)&AfL[pb][0][lane];
        const sh8 Af1 = *(const sh8*)&AfL[pb][1][lane];
        const sh8 Af2 = *(const sh8*)&AfL[pb][2][lane];
        const sh8 Af3 = *(const sh8*)&AfL[pb][3][lane];

        // G1: S1[j, t-slice] (K=128)
        f32x4 acc[4] = {z4, z4, z4, z4};
#pragma unroll
        for (int nt = 0; nt < 4; ++nt) {
            acc[nt] = __builtin_amdgcn_mfma_f32_16x16x32_bf16(Af0, Bf[0 * 4 + nt], acc[nt], 0, 0, 0);
            acc[nt] = __builtin_amdgcn_mfma_f32_16x16x32_bf16(Af1, Bf[1 * 4 + nt], acc[nt], 0, 0, 0);
            acc[nt] = __builtin_amdgcn_mfma_f32_16x16x32_bf16(Af2, Bf[2 * 4 + nt], acc[nt], 0, 0, 0);
            acc[nt] = __builtin_amdgcn_mfma_f32_16x16x32_bf16(Af3, Bf[3 * 4 + nt], acc[nt], 0, 0, 0);
        }

        // build Af(n+1) (this wave's fragment only) into the other buffer
        if (n < 63) {
            float t[8];
#pragma unroll
            for (int e = 0; e < 8; ++e)
                t[e] = isRelu ? fmaxf(iv[e] - b2f((unsigned short)raw[e]), 0.f)
                              : iv[e] + b2f((unsigned short)raw[e]);
            uint4 pk;
            pk.x = pk2(t[0], t[1]); pk.y = pk2(t[2], t[3]);
            pk.z = pk2(t[4], t[5]); pk.w = pk2(t[6], t[7]);
            AfL[nb][w][lane] = pk;
        }

        // H = relu(S1 + c) -> Hs[pb] (permuted cols t' = 64w + 4m + nt, b64 writes)
        {
            unsigned char* hw = Hs[pb] + (4 * q) * 528 + 128 * w + 8 * m;
#pragma unroll
            for (int r = 0; r < 4; ++r) {
                const float h0 = fmaxf(acc[0][r] + creg[0], 0.f);
                const float h1 = fmaxf(acc[1][r] + creg[1], 0.f);
                const float h2 = fmaxf(acc[2][r] + creg[2], 0.f);
                const float h3 = fmaxf(acc[3][r] + creg[3], 0.f);
                uint2 pk;
                pk.x = pk2(h0, h1);
                pk.y = pk2(h2, h3);
                *(uint2*)(hw + r * 528) = pk;
            }
        }

        __syncthreads();  // the ONE barrier per iter: publishes Hs[pb] and AfL[nb]

        // G2: sim[j, d-slice] (K=256, permuted k matches aw2f)
        f32x4 accS = z4;
#pragma unroll
        for (int kc = 0; kc < 8; ++kc) {
            const sh8 hf = *(const sh8*)(Hs[pb] + m * 528 + kc * 64 + 16 * q);
            accS = __builtin_amdgcn_mfma_f32_16x16x32_bf16(hf, W2f[kc], accS, 0, 0, 0);
        }
        // G3: rpe[j, d-slice] (K=64) — relu1 fragments still in registers
        f32x4 accR = z4;
        accR = __builtin_amdgcn_mfma_f32_16x16x32_bf16(Af0, P2f[0], accR, 0, 0, 0);
        accR = __builtin_amdgcn_mfma_f32_16x16x32_bf16(Af1, P2f[1], accR, 0, 0, 0);

        // online accumulation: num += exp(sim)*vv ; den += exp(sim)
        float vj[4];
        *(float4*)vj = *(const float4*)(vbase + j0 + 4 * q);
#pragma unroll
        for (int r = 0; r < 4; ++r) {
            const float ex = __expf(accS[r]);
            const float vv = accR[r] + vj[r];
            num = fmaf(ex, vv, num);
            den += ex;
        }
    }

    // reduce the 4 quad-partials (lanes m, m+16, m+32, m+48)
    num += __shfl_xor(num, 16);
    num += __shfl_xor(num, 32);
    den += __shfl_xor(den, 16);
    den += __shfl_xor(den, 32);
    if (q == 0) out[i * 64 + 16 * w + m] = num / den;
}

extern "C" void kernel_launch(void* const* d_in, const int* in_sizes, int n_in,
                              void* d_out, int out_size, void* d_ws, size_t ws_size,
                              hipStream_t stream) {
    const float* x   = (const float*)d_in[0];
    const float* pos = (const float*)d_in[1];
    const float* Wq  = (const float*)d_in[2];
    const float* Wk  = (const float*)d_in[3];
    const float* Wv  = (const float*)d_in[4];
    const float* pW1 = (const float*)d_in[5];
    const float* pb1 = (const float*)d_in[6];
    const float* pW2 = (const float*)d_in[7];
    const float* pb2 = (const float*)d_in[8];
    const float* aW1 = (const float*)d_in[9];
    const float* ab1 = (const float*)d_in[10];
    const float* aW2 = (const float*)d_in[11];
    // d_in[12] = ab2: constant over j -> cancels in per-channel softmax, unused.

    char* ws = (char*)d_ws;
    unsigned short* bextf = (unsigned short*)(ws + BEXT_OFF);
    unsigned short* aw2f  = (unsigned short*)(ws + AW2F_OFF);
    unsigned short* pw2f  = (unsigned short*)(ws + PW2F_OFF);
    float*          cArr  = (float*)(ws + CARR_OFF);
    float*          aIa   = (float*)(ws + AI_OFF);
    float*          qIa   = (float*)(ws + QI_OFF);
    float*          vPTa  = (float*)(ws + VPT_OFF);
    unsigned short* aJa   = (unsigned short*)(ws + AJ_OFF);
    unsigned short* kNa   = (unsigned short*)(ws + KN_OFF);

    prep_weights<<<209, 256, 0, stream>>>(pW2, aW1, aW2, ab1, pb2, bextf, aw2f, pw2f, cArr);
    prep_points<<<NPTS, 64, 0, stream>>>(x, pos, Wq, Wk, Wv, pW1, pb1, pb2, qIa, kNa, vPTa, aIa, aJa);
    ptl_main<<<NPTS, 256, 0, stream>>>(aIa, qIa, aJa, kNa, vPTa, bextf, aw2f, pw2f, cArr, (float*)d_out);
}

// Round 4
// 192.979 us; speedup vs baseline: 1.4315x; 1.1244x over previous
//
#include <hip/hip_runtime.h>

// PointTransformerLayer fused kernel (MI355X / gfx950) — round 4
//
// Math (verified rounds 1-2 in bf16, absmax 0.031; round-3 fp8 FAILED 0.156 —
// fp8 on G1 inputs is out of error budget, bf16 everywhere here):
//   relu1 = relu(aI_i - a_j)            aI = pos@pW1 + pb1, a = pos@pW1
//   S1    = [relu1 | (q_i - k_j)] @ [[W_pa],[aW1]]   (K=128), W_pa = pW2@aW1
//   H     = relu(S1 + c), c = ab1 + pb2@aW1          (c folded into G1 C-op)
//   sim   = H @ aW2                      (ab2 dropped: softmax-invariant)
//   rpe   = relu1 @ pW2 ; vv = (v+pb2)_j + rpe       (v folded into G3 C-op)
//   out_i[d] = sum_j exp(sim)*vv / sum_j exp(sim)
//
// Round-4 structure: j-tile 32 (2 sub-tiles of 16 per barrier), one
// __syncthreads per 32 j. VALU diet: bias/vv folded into MFMA C-operands,
// v_perm_b32 single-instr bf16 packing. Same H-LDS layout (528B stride) and
// wave-specialized A-builders as round 2.

typedef float f32x4 __attribute__((ext_vector_type(4)));
using sh8 = __attribute__((ext_vector_type(8))) short;  // 8 bf16 (4 VGPRs)

static constexpr int NPTS = 1024;

// ---- ws layout (bytes) — identical to round 2 ----
static constexpr size_t BEXT_OFF = 0;        // 4*16*64*8 bf16  = 65536 B
static constexpr size_t AW2F_OFF = 65536;    // 8*4*64*8 bf16   = 32768 B
static constexpr size_t PW2F_OFF = 98304;    // 2*4*64*8 bf16   = 8192 B
static constexpr size_t CARR_OFF = 106496;   // 256 f32         = 1024 B
static constexpr size_t AI_OFF   = 107520;   // 1024*64 f32 (+pb1)
static constexpr size_t QI_OFF   = 369664;   // 1024*64 f32
static constexpr size_t VPT_OFF  = 631808;   // 64*1024 f32 (v+pb2, transposed)
static constexpr size_t AJ_OFF   = 893952;   // 1024*64 bf16
static constexpr size_t KN_OFF   = 1025024;  // 1024*64 bf16 (negated k)

__device__ __forceinline__ unsigned short f2b_rne(float f) {
    unsigned u = __float_as_uint(f);
    u += 0x7fffu + ((u >> 16) & 1u);
    return (unsigned short)(u >> 16);
}
// trunc-pack two f32 into bf16x2 — single v_perm_b32
__device__ __forceinline__ unsigned pk2(float lo, float hi) {
    return __builtin_amdgcn_perm(__float_as_uint(hi), __float_as_uint(lo), 0x07060302);
}
__device__ __forceinline__ float b2f(unsigned short s) {
    return __uint_as_float(((unsigned)s) << 16);
}

// ---------------- combined prep: weights (blocks 0..208) + points (209..464) ----------------
__global__ void prep_all(const float* __restrict__ x, const float* __restrict__ pos,
                         const float* __restrict__ Wq, const float* __restrict__ Wk,
                         const float* __restrict__ Wv, const float* __restrict__ pW1,
                         const float* __restrict__ pb1, const float* __restrict__ pW2,
                         const float* __restrict__ pb2, const float* __restrict__ aW1,
                         const float* __restrict__ ab1, const float* __restrict__ aW2,
                         unsigned short* __restrict__ bextf, unsigned short* __restrict__ aw2f,
                         unsigned short* __restrict__ pw2f, float* __restrict__ cArr,
                         float* __restrict__ qI, unsigned short* __restrict__ kN,
                         float* __restrict__ vPT, float* __restrict__ aI,
                         unsigned short* __restrict__ aJ)
{
    const int b = blockIdx.x;
    if (b < 209) {
        const int idx = b * 256 + threadIdx.x;
        if (idx < 32768) {
            // B_ext[k][t]: k<64 -> W_pa = pW2@aW1, else aW1   (round-2 verified)
            const int k = idx >> 8, t = idx & 255;
            float val;
            if (k < 64) {
                float s = 0.f;
                for (int d = 0; d < 64; ++d) s = fmaf(pW2[k * 64 + d], aW1[d * 256 + t], s);
                val = s;
            } else {
                val = aW1[(k - 64) * 256 + t];
            }
            const int kc = k >> 5, kl = k & 31, qq = kl >> 3, e = kl & 7;
            const int ntg = t >> 4, tl = t & 15;
            bextf[(((size_t)(kc * 16 + ntg) * 64) + (qq * 16 + tl)) * 8 + e] = f2b_rne(val);
        } else if (idx < 49152) {
            // aW2 frags, K' = permuted t' matching H LDS layout (round-2 verified)
            const int r = idx - 32768;
            const int kp = r >> 6, d = r & 63;
            const int t = 64 * (kp >> 6) + 16 * (kp & 3) + ((kp >> 2) & 15);  // inverse perm
            const int kc = kp >> 5, kl = kp & 31, qq = kl >> 3, e = kl & 7;
            const int nt = d >> 4, dl = d & 15;
            aw2f[(((size_t)(kc * 4 + nt) * 64) + (qq * 16 + dl)) * 8 + e] = f2b_rne(aW2[t * 64 + d]);
        } else if (idx < 53248) {
            // pW2 frags (round-2 verified)
            const int r = idx - 49152;
            const int k = r >> 6, d = r & 63;
            const int kc = k >> 5, kl = k & 31, qq = kl >> 3, e = kl & 7;
            const int nt = d >> 4, dl = d & 15;
            pw2f[(((size_t)(kc * 4 + nt) * 64) + (qq * 16 + dl)) * 8 + e] = f2b_rne(pW2[k * 64 + d]);
        } else if (idx < 53504) {
            const int t = idx - 53248;
            float s = ab1[t];
            for (int d = 0; d < 64; ++d) s = fmaf(pb2[d], aW1[d * 256 + t], s);
            cArr[t] = s;
        }
    } else {
        // per-point prep: 4 points per block
        const int t = threadIdx.x, sub = t >> 6, d = t & 63;
        const int i = (b - 209) * 4 + sub;
        __shared__ float xs[4][64];
        xs[sub][d] = x[i * 64 + d];
        __syncthreads();
        float q = 0.f, k = 0.f, v = 0.f;
        for (int e = 0; e < 64; ++e) {
            const float xe = xs[sub][e];
            q = fmaf(xe, Wq[e * 64 + d], q);
            k = fmaf(xe, Wk[e * 64 + d], k);
            v = fmaf(xe, Wv[e * 64 + d], v);
        }
        const float a = pos[i * 2] * pW1[d] + pos[i * 2 + 1] * pW1[64 + d];
        qI[i * 64 + d] = q;
        kN[i * 64 + d] = f2b_rne(-k);
        vPT[d * NPTS + i] = v + pb2[d];
        aI[i * 64 + d] = a + pb1[d];
        aJ[i * 64 + d] = f2b_rne(a);
    }
}

// ---------------- main fused kernel: one block per query i, j-tile 32 ----------------
__global__ __launch_bounds__(256, 2) void ptl_main(
    const float* __restrict__ aI, const float* __restrict__ qI,
    const unsigned short* __restrict__ aJ, const unsigned short* __restrict__ kN,
    const float* __restrict__ vPT,
    const unsigned short* __restrict__ bextf, const unsigned short* __restrict__ aw2f,
    const unsigned short* __restrict__ pw2f, const float* __restrict__ cArr,
    float* __restrict__ out)
{
    const int i    = blockIdx.x;
    const int tid  = threadIdx.x;
    const int w    = tid >> 6;    // wave 0..3: owns t-slice [64w,64w+64), d-slice [16w,16w+16)
    const int lane = tid & 63;
    const int m    = lane & 15;
    const int q    = lane >> 4;

    // double-buffered LDS: [buf][sub]  (16 KB + 33 KB = 49 KB)
    __shared__ __align__(16) uint4 AfL[2][2][4][64];
    __shared__ __align__(16) unsigned char Hs[2][2][16 * 528];

    // constant B fragments (loaded once per block)
    sh8 Bf[16];
#pragma unroll
    for (int kc = 0; kc < 4; ++kc)
#pragma unroll
        for (int nt = 0; nt < 4; ++nt)
            Bf[kc * 4 + nt] = *(const sh8*)(bextf + ((size_t)((kc * 16 + 4 * w + nt) * 64 + lane)) * 8);
    sh8 W2f[8];
#pragma unroll
    for (int kc = 0; kc < 8; ++kc)
        W2f[kc] = *(const sh8*)(aw2f + ((size_t)((kc * 4 + w) * 64 + lane)) * 8);
    sh8 P2f[2];
#pragma unroll
    for (int kc = 0; kc < 2; ++kc)
        P2f[kc] = *(const sh8*)(pw2f + ((size_t)((kc * 4 + w) * 64 + lane)) * 8);

    // bias c splat as MFMA C-operand (folds the +c add into G1)
    f32x4 cvec[4];
#pragma unroll
    for (int nt = 0; nt < 4; ++nt) {
        const float c = cArr[64 * w + 16 * nt + m];
        cvec[nt] = (f32x4){c, c, c, c};
    }

    // builder: wave w builds A-frag k-block w (w<2: relu1 halves, w>=2: q-k halves)
    const int  half   = w & 1;
    const bool isRelu = (w < 2);
    const unsigned short* bsrc  = (isRelu ? aJ : kN) + m * 64 + half * 32 + q * 8;
    const float*          ibase = (isRelu ? aI : qI) + i * 64 + half * 32 + q * 8;
    float iv[8];
    *(float4*)(iv)     = *(const float4*)(ibase);
    *(float4*)(iv + 4) = *(const float4*)(ibase + 4);

    // prologue: build both subs of tile 0 into buffer 0
#pragma unroll
    for (int s = 0; s < 2; ++s) {
        const sh8 raw = *(const sh8*)(bsrc + (size_t)(16 * s) * 64);
        float t[8];
#pragma unroll
        for (int e = 0; e < 8; ++e)
            t[e] = isRelu ? fmaxf(iv[e] - b2f((unsigned short)raw[e]), 0.f)
                          : iv[e] + b2f((unsigned short)raw[e]);
        uint4 pk;
        pk.x = pk2(t[0], t[1]); pk.y = pk2(t[2], t[3]);
        pk.z = pk2(t[4], t[5]); pk.w = pk2(t[6], t[7]);
        AfL[0][s][w][lane] = pk;
    }
    __syncthreads();

    float num = 0.f, den = 0.f;
    const f32x4 z4 = {0.f, 0.f, 0.f, 0.f};
    const float* vbase = vPT + (size_t)(16 * w + m) * NPTS;

    for (int n = 0; n < 32; ++n) {
        const int pb = n & 1, nb = pb ^ 1;
        const int j0 = n << 5;

        // next tile's raw global loads, issued early (hidden under G1)
        sh8 raw0, raw1;
        if (n < 31) {
            raw0 = *(const sh8*)(bsrc + (size_t)(j0 + 32) * 64);
            raw1 = *(const sh8*)(bsrc + (size_t)(j0 + 48) * 64);
        }
        // v values for this tile (C-operand of G3)
        const float4 vj0 = *(const float4*)(vbase + j0 + 4 * q);
        const float4 vj1 = *(const float4*)(vbase + j0 + 16 + 4 * q);

        // ---- sub 0: G1 + H-write ----
        const sh8 A00 = *(const sh8*)&AfL[pb][0][0][lane];  // relu1 (kept live for G3)
        const sh8 A01 = *(const sh8*)&AfL[pb][0][1][lane];
        const sh8 A02 = *(const sh8*)&AfL[pb][0][2][lane];
        const sh8 A03 = *(const sh8*)&AfL[pb][0][3][lane];
        {
            f32x4 acc[4];
#pragma unroll
            for (int nt = 0; nt < 4; ++nt) {
                acc[nt] = __builtin_amdgcn_mfma_f32_16x16x32_bf16(A00, Bf[0 * 4 + nt], cvec[nt], 0, 0, 0);
                acc[nt] = __builtin_amdgcn_mfma_f32_16x16x32_bf16(A01, Bf[1 * 4 + nt], acc[nt], 0, 0, 0);
                acc[nt] = __builtin_amdgcn_mfma_f32_16x16x32_bf16(A02, Bf[2 * 4 + nt], acc[nt], 0, 0, 0);
                acc[nt] = __builtin_amdgcn_mfma_f32_16x16x32_bf16(A03, Bf[3 * 4 + nt], acc[nt], 0, 0, 0);
            }
            unsigned char* hw = Hs[pb][0] + (4 * q) * 528 + 128 * w + 8 * m;
#pragma unroll
            for (int r = 0; r < 4; ++r) {
                uint2 pk;
                pk.x = pk2(fmaxf(acc[0][r], 0.f), fmaxf(acc[1][r], 0.f));
                pk.y = pk2(fmaxf(acc[2][r], 0.f), fmaxf(acc[3][r], 0.f));
                *(uint2*)(hw + r * 528) = pk;
            }
        }

        // ---- sub 1: G1 + H-write ----
        const sh8 A10 = *(const sh8*)&AfL[pb][1][0][lane];  // relu1 (kept live for G3)
        const sh8 A11 = *(const sh8*)&AfL[pb][1][1][lane];
        const sh8 A12 = *(const sh8*)&AfL[pb][1][2][lane];
        const sh8 A13 = *(const sh8*)&AfL[pb][1][3][lane];
        {
            f32x4 acc[4];
#pragma unroll
            for (int nt = 0; nt < 4; ++nt) {
                acc[nt] = __builtin_amdgcn_mfma_f32_16x16x32_bf16(A10, Bf[0 * 4 + nt], cvec[nt], 0, 0, 0);
                acc[nt] = __builtin_amdgcn_mfma_f32_16x16x32_bf16(A11, Bf[1 * 4 + nt], acc[nt], 0, 0, 0);
                acc[nt] = __builtin_amdgcn_mfma_f32_16x16x32_bf16(A12, Bf[2 * 4 + nt], acc[nt], 0, 0, 0);
                acc[nt] = __builtin_amdgcn_mfma_f32_16x16x32_bf16(A13, Bf[3 * 4 + nt], acc[nt], 0, 0, 0);
            }
            unsigned char* hw = Hs[pb][1] + (4 * q) * 528 + 128 * w + 8 * m;
#pragma unroll
            for (int r = 0; r < 4; ++r) {
                uint2 pk;
                pk.x = pk2(fmaxf(acc[0][r], 0.f), fmaxf(acc[1][r], 0.f));
                pk.y = pk2(fmaxf(acc[2][r], 0.f), fmaxf(acc[3][r], 0.f));
                *(uint2*)(hw + r * 528) = pk;
            }
        }

        // build next tile's A-frags (this wave's k-block, both subs)
        if (n < 31) {
#pragma unroll
            for (int s = 0; s < 2; ++s) {
                const sh8 raw = s ? raw1 : raw0;
                float t[8];
#pragma unroll
                for (int e = 0; e < 8; ++e)
                    t[e] = isRelu ? fmaxf(iv[e] - b2f((unsigned short)raw[e]), 0.f)
                                  : iv[e] + b2f((unsigned short)raw[e]);
                uint4 pk;
                pk.x = pk2(t[0], t[1]); pk.y = pk2(t[2], t[3]);
                pk.z = pk2(t[4], t[5]); pk.w = pk2(t[6], t[7]);
                AfL[nb][s][w][lane] = pk;
            }
        }

        __syncthreads();  // the ONE barrier per 32 j: publishes Hs[pb][*] and AfL[nb][*]

        // ---- sub 0: G2 + G3 + online softmax ----
        {
            f32x4 accS = z4;
#pragma unroll
            for (int kc = 0; kc < 8; ++kc) {
                const sh8 hf = *(const sh8*)(Hs[pb][0] + m * 528 + kc * 64 + 16 * q);
                accS = __builtin_amdgcn_mfma_f32_16x16x32_bf16(hf, W2f[kc], accS, 0, 0, 0);
            }
            const f32x4 vc = {vj0.x, vj0.y, vj0.z, vj0.w};
            f32x4 accR = __builtin_amdgcn_mfma_f32_16x16x32_bf16(A00, P2f[0], vc, 0, 0, 0);
            accR = __builtin_amdgcn_mfma_f32_16x16x32_bf16(A01, P2f[1], accR, 0, 0, 0);
#pragma unroll
            for (int r = 0; r < 4; ++r) {
                const float ex = __expf(accS[r]);
                num = fmaf(ex, accR[r], num);
                den += ex;
            }
        }
        // ---- sub 1 ----
        {
            f32x4 accS = z4;
#pragma unroll
            for (int kc = 0; kc < 8; ++kc) {
                const sh8 hf = *(const sh8*)(Hs[pb][1] + m * 528 + kc * 64 + 16 * q);
                accS = __builtin_amdgcn_mfma_f32_16x16x32_bf16(hf, W2f[kc], accS, 0, 0, 0);
            }
            const f32x4 vc = {vj1.x, vj1.y, vj1.z, vj1.w};
            f32x4 accR = __builtin_amdgcn_mfma_f32_16x16x32_bf16(A10, P2f[0], vc, 0, 0, 0);
            accR = __builtin_amdgcn_mfma_f32_16x16x32_bf16(A11, P2f[1], accR, 0, 0, 0);
#pragma unroll
            for (int r = 0; r < 4; ++r) {
                const float ex = __expf(accS[r]);
                num = fmaf(ex, accR[r], num);
                den += ex;
            }
        }
    }

    // reduce the 4 quad-partials (lanes m, m+16, m+32, m+48)
    num += __shfl_xor(num, 16);
    num += __shfl_xor(num, 32);
    den += __shfl_xor(den, 16);
    den += __shfl_xor(den, 32);
    if (q == 0) out[i * 64 + 16 * w + m] = num / den;
}

extern "C" void kernel_launch(void* const* d_in, const int* in_sizes, int n_in,
                              void* d_out, int out_size, void* d_ws, size_t ws_size,
                              hipStream_t stream) {
    const float* x   = (const float*)d_in[0];
    const float* pos = (const float*)d_in[1];
    const float* Wq  = (const float*)d_in[2];
    const float* Wk  = (const float*)d_in[3];
    const float* Wv  = (const float*)d_in[4];
    const float* pW1 = (const float*)d_in[5];
    const float* pb1 = (const float*)d_in[6];
    const float* pW2 = (const float*)d_in[7];
    const float* pb2 = (const float*)d_in[8];
    const float* aW1 = (const float*)d_in[9];
    const float* ab1 = (const float*)d_in[10];
    const float* aW2 = (const float*)d_in[11];
    // d_in[12] = ab2: constant over j -> cancels in per-channel softmax, unused.

    char* ws = (char*)d_ws;
    unsigned short* bextf = (unsigned short*)(ws + BEXT_OFF);
    unsigned short* aw2f  = (unsigned short*)(ws + AW2F_OFF);
    unsigned short* pw2f  = (unsigned short*)(ws + PW2F_OFF);
    float*          cArr  = (float*)(ws + CARR_OFF);
    float*          aIa   = (float*)(ws + AI_OFF);
    float*          qIa   = (float*)(ws + QI_OFF);
    float*          vPTa  = (float*)(ws + VPT_OFF);
    unsigned short* aJa   = (unsigned short*)(ws + AJ_OFF);
    unsigned short* kNa   = (unsigned short*)(ws + KN_OFF);

    prep_all<<<465, 256, 0, stream>>>(x, pos, Wq, Wk, Wv, pW1, pb1, pW2, pb2, aW1, ab1, aW2,
                                      bextf, aw2f, pw2f, cArr, qIa, kNa, vPTa, aIa, aJa);
    ptl_main<<<NPTS, 256, 0, stream>>>(aIa, qIa, aJa, kNa, vPTa, bextf, aw2f, pw2f, cArr,
                                       (float*)d_out);
}